// Round 1
// baseline (618.021 us; speedup 1.0000x reference)
//
#include <hip/hip_runtime.h>
#include <math.h>

#define BB 8
#define QQ 2048
#define GG 128
#define CC 512

// ---------------------------------------------------------------------------
// Kernel A: final_cost[b][q][g] = 2*diff(sem[b,q,label[b,g]]) + 5*center + size - 2*gious
// Arithmetic replicates the numpy/jax f32 evaluation order exactly; FMA
// contraction disabled so each mul/add rounds separately like XLA's elementwise.
// ---------------------------------------------------------------------------
__global__ __launch_bounds__(256) void cost_kernel(
    const float* __restrict__ sem,      // B,Q,C
    const float* __restrict__ center,   // B,Q,G
    const float* __restrict__ size_,    // B,Q,G
    const float* __restrict__ gious,    // B,Q,G
    const int*   __restrict__ labels,   // B,G (int64 in ref -> int32 here)
    float* __restrict__ final_cost)     // B,Q,G
{
#pragma clang fp contract(off)
    int idx = blockIdx.x * blockDim.x + threadIdx.x;
    const int total = BB * QQ * GG;
    if (idx >= total) return;
    int g  = idx % GG;
    int bq = idx / GG;      // b*Q + q
    int b  = bq / QQ;
    int lab = labels[b * GG + g];
    float x = sem[bq * CC + lab];
    float p = 1.0f / (1.0f + expf(-x));
    // neg = (1-ALPHA) * p^2 * -log1p(-(p - 1e-8))
    float t   = p - 1e-8f;
    float neg = (0.75f * (p * p)) * (-log1pf(-t));
    // pos = ALPHA * (1-p)^2 * -log(p + 1e-8)
    float omp = 1.0f - p;
    float pos = (0.25f * (omp * omp)) * (-logf(p + 1e-8f));
    float diff = pos - neg;
    // (((2*diff) + (5*center)) + (1*size)) + (2*(-gious))
    float c0 = (2.0f * diff) + (5.0f * center[idx]);
    float c1 = c0 + (1.0f * size_[idx]);
    float cost = c1 + (2.0f * (-gious[idx]));
    final_cost[idx] = cost;
}

// ---------------------------------------------------------------------------
// Kernel B: exact replica of the reference's (degenerate) Jonker-Volgenant.
// Note: in the reference, minv1/way1 are local copies never written back, so
// minv stays +inf and way stays 0. Effective algorithm per row i:
//   j0 = 0; p[0] = i
//   loop: used[j0]=1; i0=p[j0]
//         jmin = argmin over free j of (C[i0-1][j-1] - u[i0] - v[j]), first-idx tie
//         delta = that min; for used j: u[p[j]] += delta, v[j] -= delta  (incl col 0)
//         j0 = jmin; if p[j0]==0: p[j0]=i; done
// All potential arithmetic in float64, cost loaded f32->f64 (exact cast),
// matching np.asarray(cost, dtype=np.float64).
// One block per batch. cost read transposed straight out of d_out (L2-resident).
// ---------------------------------------------------------------------------
__global__ __launch_bounds__(256) void hungarian_kernel(
    const float* __restrict__ final_cost, // B,Q,G
    const int*   __restrict__ nactual,    // B
    float* __restrict__ out_inds,         // B,Q
    float* __restrict__ out_mask)         // B,Q
{
    __shared__ double v[QQ + 1];
    __shared__ double u[GG + 1];
    __shared__ int    p[QQ + 1];
    __shared__ unsigned char used[QQ + 1];
    __shared__ double red_val[4];
    __shared__ int    red_idx[4];
    __shared__ int    s_j0, s_jmin, s_done;
    __shared__ double s_delta;

    const int b   = blockIdx.x;
    const int tid = threadIdx.x;
    int n = nactual[b];
    if (n < 0) n = 0;
    if (n > GG) n = GG;
    const float* costb = final_cost + (size_t)b * QQ * GG;

    for (int j = tid; j <= QQ; j += 256) { v[j] = 0.0; p[j] = 0; }
    for (int i = tid; i <= GG; i += 256) u[i] = 0.0;
    __syncthreads();

    for (int i = 1; i <= n; ++i) {
        for (int j = tid; j <= QQ; j += 256) used[j] = 0;
        if (tid == 0) { p[0] = i; s_j0 = 0; }
        __syncthreads();

        while (true) {
            if (tid == 0) used[s_j0] = 1;
            __syncthreads();                      // used + s_j0 visible
            const int    i0  = p[s_j0];
            const double ui0 = u[i0];

            // local argmin over my strided columns (ascending j per thread,
            // so strict < keeps the smallest j automatically)
            double bestv = INFINITY;
            int    bestj = 0x7fffffff;
            for (int j = tid + 1; j <= QQ; j += 256) {
                if (!used[j]) {
                    double cv = (double)costb[(size_t)(j - 1) * GG + (i0 - 1)] - ui0 - v[j];
                    if (cv < bestv) { bestv = cv; bestj = j; }
                }
            }
            // wave reduce (64 lanes), tie -> smaller j
            for (int off = 32; off > 0; off >>= 1) {
                double ov = __shfl_down(bestv, off);
                int    oj = __shfl_down(bestj, off);
                if (ov < bestv || (ov == bestv && oj < bestj)) { bestv = ov; bestj = oj; }
            }
            const int wave = tid >> 6;
            if ((tid & 63) == 0) { red_val[wave] = bestv; red_idx[wave] = bestj; }
            __syncthreads();
            if (tid == 0) {
                double dv = red_val[0]; int dj = red_idx[0];
                for (int w = 1; w < 4; ++w) {
                    if (red_val[w] < dv || (red_val[w] == dv && red_idx[w] < dj)) {
                        dv = red_val[w]; dj = red_idx[w];
                    }
                }
                s_delta = dv; s_jmin = dj;
            }
            __syncthreads();
            const double delta = s_delta;
            // potentials update over used columns (includes column 0)
            for (int j = tid; j <= QQ; j += 256) {
                if (used[j]) { v[j] -= delta; u[p[j]] += delta; }
            }
            __syncthreads();
            if (tid == 0) {
                int jm = s_jmin;
                if (jm < 1 || jm > QQ) {          // safety (should not happen)
                    s_done = 1;
                } else if (p[jm] == 0) {
                    p[jm] = i;                     // degenerate augmentation: p[0]=i chain
                    s_done = 1;
                } else {
                    s_j0 = jm; s_done = 0;
                }
            }
            __syncthreads();
            if (s_done) break;
        }
    }

    // outputs: proposal q matched iff p[q+1] > 0, gt index = p[q+1]-1
    for (int q = tid; q < QQ; q += 256) {
        int pj = p[q + 1];
        out_inds[(size_t)b * QQ + q] = (pj > 0) ? (float)(pj - 1) : 0.0f;
        out_mask[(size_t)b * QQ + q] = (pj > 0) ? 1.0f : 0.0f;
    }
}

extern "C" void kernel_launch(void* const* d_in, const int* in_sizes, int n_in,
                              void* d_out, int out_size, void* d_ws, size_t ws_size,
                              hipStream_t stream) {
    const float* sem     = (const float*)d_in[0];
    const float* center  = (const float*)d_in[1];
    const float* size_   = (const float*)d_in[2];
    const float* gious   = (const float*)d_in[3];
    const int*   labels  = (const int*)d_in[4];
    const int*   nactual = (const int*)d_in[5];

    float* out        = (float*)d_out;
    float* out_inds   = out;                    // B*Q
    float* out_mask   = out + BB * QQ;          // B*Q
    float* final_cost = out + 2 * BB * QQ;      // B*Q*G

    const int total = BB * QQ * GG;
    cost_kernel<<<(total + 255) / 256, 256, 0, stream>>>(
        sem, center, size_, gious, labels, final_cost);
    hungarian_kernel<<<BB, 256, 0, stream>>>(
        final_cost, nactual, out_inds, out_mask);
}

// Round 2
// 456.198 us; speedup vs baseline: 1.3547x; 1.3547x over previous
//
#include <hip/hip_runtime.h>
#include <math.h>

#define BB 8
#define QQ 2048
#define GG 128
#define CC 512

// ---------------------------------------------------------------------------
// Kernel A (fused): final_cost[b][q][g] in (b,q,g) layout (output) AND
// costT[b][g][q] transposed copy in workspace (for coalesced hungarian scans).
// Arithmetic replicates the numpy f32 evaluation order exactly; contraction off.
// Grid: 8 b * 64 qtiles, 256 threads; each block: 32 q x 128 g tile.
// ---------------------------------------------------------------------------
__global__ __launch_bounds__(256) void cost_kernel(
    const float* __restrict__ sem,      // B,Q,C
    const float* __restrict__ center,   // B,Q,G
    const float* __restrict__ size_,    // B,Q,G
    const float* __restrict__ gious,    // B,Q,G
    const int*   __restrict__ labels,   // B,G
    float* __restrict__ final_cost,     // B,Q,G
    float* __restrict__ costT,          // B,G,Q (workspace) or nullptr
    int write_t)
{
#pragma clang fp contract(off)
    __shared__ int   lab[GG];
    __shared__ float tile[32][GG + 1];   // +1 pad: conflict-free column reads
    const int t  = threadIdx.x;
    const int b  = blockIdx.x >> 6;          // 64 q-tiles per batch
    const int q0 = (blockIdx.x & 63) << 5;   // tile origin in q
    if (t < GG) lab[t] = labels[b * GG + t];
    __syncthreads();

    for (int k = 0; k < 16; ++k) {
        int lin = k * 256 + t;
        int qi  = lin >> 7;        // 0..31
        int g   = lin & 127;
        size_t bq  = (size_t)b * QQ + (q0 + qi);
        float x = sem[bq * CC + lab[g]];
        float p = 1.0f / (1.0f + expf(-x));
        float tt  = p - 1e-8f;
        float neg = (0.75f * (p * p)) * (-log1pf(-tt));
        float omp = 1.0f - p;
        float pos = (0.25f * (omp * omp)) * (-logf(p + 1e-8f));
        float diff = pos - neg;
        size_t idx = bq * GG + g;
        float c0 = (2.0f * diff) + (5.0f * center[idx]);
        float c1 = c0 + (1.0f * size_[idx]);
        float cost = c1 + (2.0f * (-gious[idx]));
        final_cost[idx] = cost;
        tile[qi][g] = cost;
    }
    if (!write_t) return;
    __syncthreads();
    // write costT[b][g][q0..q0+31]: 32 consecutive floats per 32 lanes (128B seg)
    for (int k = 0; k < 16; ++k) {
        int lin = k * 256 + t;
        int g   = lin >> 5;        // 0..127
        int qi  = lin & 31;
        costT[((size_t)b * GG + g) * QQ + (q0 + qi)] = tile[qi][g];
    }
}

// ---------------------------------------------------------------------------
// Kernel B: exact replica of the reference's degenerate Jonker-Volgenant.
// Effective per-row-i semantics (minv/way copies in the reference are dead):
//   i0 = i
//   loop: jmin = argmin over non-used cols c of (C[i0][c] - u[i0] - v[c]),
//         first-index tie-break; delta = that min;
//         u[i] += delta (col-0), and for each used col c: v[c]-=delta, u[p0[c]]+=delta;
//         if p0[jmin]==0: p0[jmin]=i, done; else mark jmin used, i0 = p0[jmin].
// v persists across rows. All potential math in float64 (exact f32->f64 cast).
// Structure: 256 threads, 8 cols/thread (c = tid + s*256), v/used in REGISTERS
// (static indexing only), 2 barriers per step, p0 assignment deferred one
// phase so the done-decision read of p0[jmin] is race-free and uniform.
// ---------------------------------------------------------------------------
__global__ __launch_bounds__(256) void hungarian_kernel(
    const float* __restrict__ costm,    // costT (g-major) or final_cost (q-major)
    const int*   __restrict__ nactual,  // B
    float* __restrict__ out_inds,       // B,Q
    float* __restrict__ out_mask,       // B,Q
    int strideRow, int strideCol)
{
    __shared__ double u[GG + 1];        // row potentials, rows 1..n
    __shared__ int    p0[QQ];           // col -> assigned row (0 = free)
    __shared__ double red_val[4];
    __shared__ int    red_idx[4];

    const int b   = blockIdx.x;
    const int tid = threadIdx.x;
    int n = nactual[b];
    if (n < 0) n = 0;
    if (n > GG) n = GG;
    const float* cb = costm + (size_t)b * QQ * GG;

    double v[8];
    #pragma unroll
    for (int s = 0; s < 8; ++s) v[s] = 0.0;
    int usedm = 0;
    for (int c = tid; c < QQ; c += 256) p0[c] = 0;
    for (int i = tid; i <= GG; i += 256) u[i] = 0.0;

    int pend_c = -1, pend_i = 0;        // deferred p0 assignment (tid 0 only)

    for (int i = 1; i <= n; ++i) {
        usedm = 0;
        int i0 = i;
        while (true) {
            __syncthreads();            // phase 1 start: publishes u/p0 updates
            if (tid == 0 && pend_c >= 0) { p0[pend_c] = pend_i; pend_c = -1; }
            const double ui0 = u[i0];
            const float* rowp = cb + (size_t)(i0 - 1) * strideRow;

            double bestv = INFINITY;
            int    bestc = 0x7fffffff;
            #pragma unroll
            for (int s = 0; s < 8; ++s) {
                int c = tid + (s << 8);
                double cv = (double)rowp[(size_t)c * strideCol] - ui0 - v[s];
                bool us = (usedm >> s) & 1;
                if (!us && cv < bestv) { bestv = cv; bestc = c; }
            }
            // wave reduce, tie -> smaller c
            for (int off = 32; off > 0; off >>= 1) {
                double ov = __shfl_down(bestv, off);
                int    oc = __shfl_down(bestc, off);
                if (ov < bestv || (ov == bestv && oc < bestc)) { bestv = ov; bestc = oc; }
            }
            if ((tid & 63) == 0) { red_val[tid >> 6] = bestv; red_idx[tid >> 6] = bestc; }
            __syncthreads();            // phase 2 start: partials + p0 stable

            // redundant final reduce on every thread (no broadcast barrier)
            double dv = red_val[0]; int dc = red_idx[0];
            #pragma unroll
            for (int w = 1; w < 4; ++w) {
                if (red_val[w] < dv || (red_val[w] == dv && red_idx[w] < dc)) {
                    dv = red_val[w]; dc = red_idx[w];
                }
            }
            const int pr   = p0[dc];    // no writes to p0 in this phase
            const int done = (pr == 0);

            // potentials: col 0 (thread 0) + my used cols (distinct u entries)
            if (tid == 0) u[i] += dv;
            #pragma unroll
            for (int s = 0; s < 8; ++s) {
                if ((usedm >> s) & 1) {
                    v[s] -= dv;
                    u[p0[tid + (s << 8)]] += dv;
                }
            }
            if (done) {
                if (tid == 0) { pend_c = dc; pend_i = i; }  // defer p0[dc]=i
                break;
            }
            if ((dc & 255) == tid) usedm |= 1 << (dc >> 8);
            i0 = pr;
        }
    }
    if (tid == 0 && pend_c >= 0) p0[pend_c] = pend_i;
    __syncthreads();

    for (int c = tid; c < QQ; c += 256) {
        int pr = p0[c];
        out_inds[(size_t)b * QQ + c] = (pr > 0) ? (float)(pr - 1) : 0.0f;
        out_mask[(size_t)b * QQ + c] = (pr > 0) ? 1.0f : 0.0f;
    }
}

extern "C" void kernel_launch(void* const* d_in, const int* in_sizes, int n_in,
                              void* d_out, int out_size, void* d_ws, size_t ws_size,
                              hipStream_t stream) {
    const float* sem     = (const float*)d_in[0];
    const float* center  = (const float*)d_in[1];
    const float* size_   = (const float*)d_in[2];
    const float* gious   = (const float*)d_in[3];
    const int*   labels  = (const int*)d_in[4];
    const int*   nactual = (const int*)d_in[5];

    float* out        = (float*)d_out;
    float* out_inds   = out;                    // B*Q
    float* out_mask   = out + BB * QQ;          // B*Q
    float* final_cost = out + 2 * BB * QQ;      // B*Q*G

    const size_t t_bytes = (size_t)BB * GG * QQ * sizeof(float);
    const int use_t = (ws_size >= t_bytes) ? 1 : 0;
    float* costT = use_t ? (float*)d_ws : nullptr;

    cost_kernel<<<BB * 64, 256, 0, stream>>>(
        sem, center, size_, gious, labels, final_cost, costT, use_t);

    if (use_t) {
        hungarian_kernel<<<BB, 256, 0, stream>>>(
            costT, nactual, out_inds, out_mask, QQ, 1);
    } else {
        hungarian_kernel<<<BB, 256, 0, stream>>>(
            final_cost, nactual, out_inds, out_mask, 1, GG);
    }
}

// Round 4
// 342.136 us; speedup vs baseline: 1.8064x; 1.3334x over previous
//
#include <hip/hip_runtime.h>
#include <math.h>

#define BB 8
#define QQ 2048
#define GG 128
#define CC 512

// ---------------------------------------------------------------------------
// Kernel A (fused): final_cost[b][q][g] (output) + costT[b][g][q] (workspace,
// coalesced rows for the hungarian scans). Exact numpy f32 evaluation order.
// ---------------------------------------------------------------------------
__global__ __launch_bounds__(256) void cost_kernel(
    const float* __restrict__ sem,      // B,Q,C
    const float* __restrict__ center,   // B,Q,G
    const float* __restrict__ size_,    // B,Q,G
    const float* __restrict__ gious,    // B,Q,G
    const int*   __restrict__ labels,   // B,G
    float* __restrict__ final_cost,     // B,Q,G
    float* __restrict__ costT,          // B,G,Q (workspace) or nullptr
    int write_t)
{
#pragma clang fp contract(off)
    __shared__ int   lab[GG];
    __shared__ float tile[32][GG + 1];
    const int t  = threadIdx.x;
    const int b  = blockIdx.x >> 6;
    const int q0 = (blockIdx.x & 63) << 5;
    if (t < GG) lab[t] = labels[b * GG + t];
    __syncthreads();

    for (int k = 0; k < 16; ++k) {
        int lin = k * 256 + t;
        int qi  = lin >> 7;
        int g   = lin & 127;
        size_t bq  = (size_t)b * QQ + (q0 + qi);
        float x = sem[bq * CC + lab[g]];
        float p = 1.0f / (1.0f + expf(-x));
        float tt  = p - 1e-8f;
        float neg = (0.75f * (p * p)) * (-log1pf(-tt));
        float omp = 1.0f - p;
        float pos = (0.25f * (omp * omp)) * (-logf(p + 1e-8f));
        float diff = pos - neg;
        size_t idx = bq * GG + g;
        float c0 = (2.0f * diff) + (5.0f * center[idx]);
        float c1 = c0 + (1.0f * size_[idx]);
        float cost = c1 + (2.0f * (-gious[idx]));
        final_cost[idx] = cost;
        tile[qi][g] = cost;
    }
    if (!write_t) return;
    __syncthreads();
    for (int k = 0; k < 16; ++k) {
        int lin = k * 256 + t;
        int g   = lin >> 5;
        int qi  = lin & 31;
        costT[((size_t)b * GG + g) * QQ + (q0 + qi)] = tile[qi][g];
    }
}

// ---------------------------------------------------------------------------
// Kernel B: reference's degenerate JV, single wave per batch.
// Exact semantics per chain step (row i, current row i0):
//   key_c = ((double)C[i0][c] - u[i0]) - v[c]  over non-used cols, argmin with
//   first-index ties; delta = key_min; u[i]+=delta; for used cols c:
//   v[c]-=delta, u[p0[c]]+=delta; done when chosen col free -> p0[c]=i.
// Split: A = untouched cols (v==0 exactly, key order == f32 C order; f32 scan
// over 32 contiguous cols/lane) ; B = S-list of ever-touched cols (exact f64 v
// in LDS). Combined lexicographic (f64 key, col) butterfly over 64 lanes.
// ---------------------------------------------------------------------------
template<bool VEC>
__global__ __launch_bounds__(64) void hungarian_kernel(
    const float* __restrict__ costm,    // VEC: costT [b][g][q]; else final_cost [b][q][g]
    const int*   __restrict__ nactual,
    float* __restrict__ out_inds,
    float* __restrict__ out_mask)
{
    __shared__ double u[GG + 2];               // row potentials (1..128)
    __shared__ double Sv[QQ];                  // v for touched cols
    __shared__ unsigned short Sc[QQ];          // S slot -> col
    __shared__ unsigned short sIdx[QQ];        // col -> S slot (valid iff touched)
    __shared__ unsigned short p0[QQ];          // col -> row (0 = free)
    __shared__ unsigned short chain[GG];       // used cols this row
    __shared__ unsigned int usedBits[QQ / 32];
    __shared__ unsigned int touchedBits[QQ / 32];

    const int b    = blockIdx.x;
    const int lane = threadIdx.x;              // 0..63
    int n = nactual[b];
    if (n < 0) n = 0;
    if (n > GG) n = GG;
    const float* cb = costm + (size_t)b * QQ * GG;
    const double DINF = __builtin_huge_val();

    for (int t = lane; t < QQ; t += 64) p0[t] = 0;
    for (int t = lane; t < GG + 2; t += 64) u[t] = 0.0;
    touchedBits[lane] = 0;
    unsigned excl = 0;                          // touched bits for my 32 cols
    int S_len = 0;
    __syncthreads();

    for (int i = 1; i <= n; ++i) {
        usedBits[lane] = 0;
        int chainLen = 0;
        int i0 = i;
        __syncthreads();

        while (true) {
            const double ui0 = u[i0];
            const float* rowp = VEC ? (cb + (size_t)(i0 - 1) * QQ) : (cb + (i0 - 1));

            // ---- A: f32 argmin over my 32 contiguous untouched cols ----
            float bestA = __builtin_huge_valf();
            int   colA  = 1 << 30;
            if (VEC) {
                const float4* rp4 = reinterpret_cast<const float4*>(rowp) + (lane << 3);
                #pragma unroll
                for (int k = 0; k < 8; ++k) {
                    float4 q4 = rp4[k];
                    int cbase = (lane << 5) + (k << 2);
                    if (((excl >> (4 * k + 0)) & 1u) == 0 && q4.x < bestA) { bestA = q4.x; colA = cbase + 0; }
                    if (((excl >> (4 * k + 1)) & 1u) == 0 && q4.y < bestA) { bestA = q4.y; colA = cbase + 1; }
                    if (((excl >> (4 * k + 2)) & 1u) == 0 && q4.z < bestA) { bestA = q4.z; colA = cbase + 2; }
                    if (((excl >> (4 * k + 3)) & 1u) == 0 && q4.w < bestA) { bestA = q4.w; colA = cbase + 3; }
                }
            } else {
                #pragma unroll 8
                for (int k = 0; k < 32; ++k) {
                    float cv = rowp[(size_t)((lane << 5) + k) * GG];
                    if (((excl >> k) & 1u) == 0 && cv < bestA) { bestA = cv; colA = (lane << 5) + k; }
                }
            }
            double kb  = (colA < (1 << 30)) ? ((double)bestA - ui0) : DINF;
            int    cbst = colA;

            // ---- B: exact f64 over touched, non-used cols (S-list) ----
            #pragma unroll 4
            for (int t = lane; t < S_len; t += 64) {
                int c = Sc[t];
                float cf = VEC ? rowp[c] : rowp[(size_t)c * GG];
                bool us = (usedBits[c >> 5] >> (c & 31)) & 1u;
                double key = ((double)cf - ui0) - Sv[t];
                if (!us && (key < kb || (key == kb && c < cbst))) { kb = key; cbst = c; }
            }

            // ---- 64-lane lexicographic (key, col) allreduce ----
            #pragma unroll
            for (int off = 1; off < 64; off <<= 1) {
                double ok = __shfl_xor(kb, off);
                int    oc = __shfl_xor(cbst, off);
                if (ok < kb || (ok == kb && oc < cbst)) { kb = ok; cbst = oc; }
            }
            const double delta = kb;
            const int    dc    = cbst;
            const int    pr    = p0[dc];
            const bool   inS   = (touchedBits[dc >> 5] >> (dc & 31)) & 1u;
            __syncthreads();                    // reads done before updates

            // ---- potentials: chain cols + virtual col 0 ----
            for (int t = lane; t < chainLen; t += 64) {
                int c = chain[t];
                Sv[sIdx[c]] -= delta;
                u[p0[c]]    += delta;
            }
            if (lane == 63) u[i] += delta;

            if (pr == 0) {
                if (lane == 0) p0[dc] = (unsigned short)i;   // augment (chain collapses)
                __syncthreads();
                break;
            }
            if (lane == 0) {
                if (!inS) { Sc[S_len] = (unsigned short)dc; Sv[S_len] = 0.0;
                            sIdx[dc] = (unsigned short)S_len;
                            touchedBits[dc >> 5] |= 1u << (dc & 31); }
                chain[chainLen] = (unsigned short)dc;
                usedBits[dc >> 5] |= 1u << (dc & 31);
            }
            if (!inS && lane == (dc >> 5)) excl |= 1u << (dc & 31);
            if (!inS) S_len++;
            chainLen++;
            i0 = pr;
            __syncthreads();
        }
    }

    for (int c = lane; c < QQ; c += 64) {
        int pr = p0[c];
        out_inds[(size_t)b * QQ + c] = (pr > 0) ? (float)(pr - 1) : 0.0f;
        out_mask[(size_t)b * QQ + c] = (pr > 0) ? 1.0f : 0.0f;
    }
}

extern "C" void kernel_launch(void* const* d_in, const int* in_sizes, int n_in,
                              void* d_out, int out_size, void* d_ws, size_t ws_size,
                              hipStream_t stream) {
    const float* sem     = (const float*)d_in[0];
    const float* center  = (const float*)d_in[1];
    const float* size_   = (const float*)d_in[2];
    const float* gious   = (const float*)d_in[3];
    const int*   labels  = (const int*)d_in[4];
    const int*   nactual = (const int*)d_in[5];

    float* out        = (float*)d_out;
    float* out_inds   = out;
    float* out_mask   = out + BB * QQ;
    float* final_cost = out + 2 * BB * QQ;

    const size_t t_bytes = (size_t)BB * GG * QQ * sizeof(float);
    const int use_t = (ws_size >= t_bytes) ? 1 : 0;
    float* costT = use_t ? (float*)d_ws : nullptr;

    cost_kernel<<<BB * 64, 256, 0, stream>>>(
        sem, center, size_, gious, labels, final_cost, costT, use_t);

    if (use_t) {
        hungarian_kernel<true><<<BB, 64, 0, stream>>>(costT, nactual, out_inds, out_mask);
    } else {
        hungarian_kernel<false><<<BB, 64, 0, stream>>>(final_cost, nactual, out_inds, out_mask);
    }
}